// Round 13
// baseline (267.914 us; speedup 1.0000x reference)
//
#include <hip/hip_runtime.h>
#include <math.h>

#define NNODES 50000
#define NEDGE  800000
#define NG     3
#define D      128
#define GE     (NG*NEDGE)            // 2,400,000 combined edges
#define NBUK   782                   // buckets of 64 rows (row >> 6)
#define CH     4096                  // edges per k_bin block
#define NBLK   ((GE + CH - 1) / CH)  // 586
#define CAP2   3456                  // bucket record cap (mean 3069, +7 sigma)
#define NKEY2  1024                  // agg2 sort keys: lr*16 + (col>>12)

typedef __attribute__((ext_vector_type(8))) short bf16x8;
typedef __attribute__((ext_vector_type(4))) float f32x4;

// fp32 -> bf16 round-to-nearest-even (no NaN inputs here)
__device__ __forceinline__ unsigned short f2bf(float f) {
    unsigned u = __float_as_uint(f);
    return (unsigned short)((u + 0x7fffu + ((u >> 16) & 1u)) >> 16);
}

// ---------------------------------------------------------------------------
// K0: swizzle W into bf16 MFMA B-fragment order (proven r10).
// ---------------------------------------------------------------------------
__global__ void k_wprep(const float* __restrict__ W, uint4* __restrict__ Wf) {
    const int t = threadIdx.x;
    for (int i = t; i < 2048; i += 256) {
        const int nt   = i >> 8;
        const int kc   = (i >> 6) & 3;
        const int lane = i & 63;
        const int n  = nt * 16 + (lane & 15);
        const int k0 = kc * 32 + (lane >> 4) * 8;
        const float* src = W + (size_t)n * 128 + k0;
        unsigned u0 = (unsigned)f2bf(src[0]) | ((unsigned)f2bf(src[1]) << 16);
        unsigned u1 = (unsigned)f2bf(src[2]) | ((unsigned)f2bf(src[3]) << 16);
        unsigned u2 = (unsigned)f2bf(src[4]) | ((unsigned)f2bf(src[5]) << 16);
        unsigned u3 = (unsigned)f2bf(src[6]) | ((unsigned)f2bf(src[7]) << 16);
        Wf[i] = make_uint4(u0, u1, u2, u3);
    }
}

// ---------------------------------------------------------------------------
// K1: h = X @ W^T via bf16 MFMA 16x16x32 (proven r10, absmax 0.125).
// ---------------------------------------------------------------------------
__global__ __launch_bounds__(256) void k_gemm(const float* __restrict__ X,
                                              const uint4* __restrict__ Wf,
                                              unsigned short* __restrict__ hb16) {
    __shared__ uint4 Wl[2048];   // 32KB
    const int t = threadIdx.x;
#pragma unroll
    for (int j = 0; j < 8; ++j) Wl[t + j * 256] = Wf[t + j * 256];
    __syncthreads();

    const int w    = t >> 6;
    const int lane = t & 63;
    const int q    = lane >> 4;
    const int ml   = lane & 15;
    const int m0   = blockIdx.x * 64 + w * 16;

    int xr = m0 + ml; if (xr >= NNODES) xr = NNODES - 1;
    const float* xrow = X + (size_t)xr * 128;

    bf16x8 xf[4];
#pragma unroll
    for (int kc = 0; kc < 4; ++kc) {
        const int k0 = kc * 32 + q * 8;
        float4 a = *(const float4*)(xrow + k0);
        float4 b = *(const float4*)(xrow + k0 + 4);
        bf16x8 v;
        v[0] = (short)f2bf(a.x); v[1] = (short)f2bf(a.y);
        v[2] = (short)f2bf(a.z); v[3] = (short)f2bf(a.w);
        v[4] = (short)f2bf(b.x); v[5] = (short)f2bf(b.y);
        v[6] = (short)f2bf(b.z); v[7] = (short)f2bf(b.w);
        xf[kc] = v;
    }

#pragma unroll
    for (int nt = 0; nt < 8; ++nt) {
        f32x4 acc = {0.f, 0.f, 0.f, 0.f};
#pragma unroll
        for (int kc = 0; kc < 4; ++kc) {
            const bf16x8 wf = *(const bf16x8*)&Wl[(nt * 4 + kc) * 64 + lane];
            acc = __builtin_amdgcn_mfma_f32_16x16x32_bf16(xf[kc], wf, acc, 0, 0, 0);
        }
#pragma unroll
        for (int r = 0; r < 4; ++r) {
            const int row = m0 + q * 4 + r;
            if (row < NNODES)
                hb16[(size_t)row * 128 + nt * 16 + ml] = f2bf(acc[r]);
        }
    }
}

// ---------------------------------------------------------------------------
// K2: per-block bucket binning (r11 proven version): rank capture from
// pass-1 atomicAdd, shuffle scan over 1024, grouped L2-resident writes,
// off1T transposed [bucket][blk]. ZERO global atomics.
// ---------------------------------------------------------------------------
__global__ __launch_bounds__(256) void k_bin(const int* __restrict__ rows,
                                             const int* __restrict__ cols,
                                             const float* __restrict__ vals,
                                             const float* __restrict__ alpha,
                                             uint2* __restrict__ out1,
                                             int* __restrict__ off1T) {
    __shared__ uint2 stg[CH];              // 32768 B
    __shared__ unsigned short rnk[CH];     //  8192 B
    __shared__ int sE[1024];               //  4096 B
    __shared__ int wtot[4];
    const int t   = threadIdx.x;
    const int blk = blockIdx.x;
    const int start = blk * CH;
    const int end   = (start + CH < GE) ? (start + CH) : GE;

    const float g0 = 1.0f / (1.0f + __expf(-alpha[0]));
    const float g1 = 1.0f / (1.0f + __expf(-alpha[1]));
    const float g2 = 1.0f / (1.0f + __expf(-alpha[2]));

#pragma unroll
    for (int j = 0; j < 4; ++j) sE[t + j * 256] = 0;
    __syncthreads();

    // pass 1: read globals once, pack record, histogram + rank capture
    for (int idx = start + t, k = t; idx < end; idx += 256, k += 256) {
        const int r = rows[idx];
        const int c = cols[idx];
        const float v = vals[idx];
        const float gv = v * (idx < NEDGE ? g0 : (idx < 2 * NEDGE ? g1 : g2));
        uint2 rec;
        rec.x = ((unsigned)r << 16) | (unsigned)c;   // both < 65536
        rec.y = __float_as_uint(gv);
        stg[k] = rec;
        rnk[k] = (unsigned short)atomicAdd(&sE[r >> 6], 1);
    }
    __syncthreads();

    // shuffle-based exclusive scan over 1024 (thread t owns sE[4t..4t+3])
    const int lane = t & 63;
    const int w    = t >> 6;
    int4 v4 = *(int4*)&sE[4 * t];
    const int l1 = v4.x + v4.y;
    const int l2 = l1 + v4.z;
    const int l3 = l2 + v4.w;
    int s = l3;
#pragma unroll
    for (int off = 1; off < 64; off <<= 1) {
        int n = __shfl_up(s, off);
        if (lane >= off) s += n;
    }
    if (lane == 63) wtot[w] = s;
    const int waveExcl = s - l3;
    __syncthreads();
    int cross = 0;
    for (int j = 0; j < w; ++j) cross += wtot[j];
    const int b0 = cross + waveExcl;
    int4 e4;
    e4.x = b0; e4.y = b0 + v4.x; e4.z = b0 + l1; e4.w = b0 + l2;
    *(int4*)&sE[4 * t] = e4;
    __syncthreads();

    // transposed offsets: off1T[b][blk] (+ sentinel row NBUK)
    for (int b = t; b < NBUK; b += 256)
        off1T[(size_t)b * NBLK + blk] = sE[b];
    if (t == 0) off1T[(size_t)NBUK * NBLK + blk] = end - start;

    // pass 2: position = base[bucket] + rank, grouped write, no atomics
    for (int idx = start + t, k = t; idx < end; idx += 256, k += 256) {
        const uint2 rec = stg[k];
        const int b = (int)(rec.x >> 22);            // row>>6
        out1[(size_t)blk * CH + sE[b] + (int)rnk[k]] = rec;
    }
}

// ---------------------------------------------------------------------------
// K3: one block (512 thr) per 64-row bucket. r10 structure + COLUMN-SORTED
// permutation: sort key = lr*16 + (col>>12) (1024 keys). Rank captured from
// the copy-pass atomicAdd; permutation built atomic-free as
// order[kbase[key]+rnk[p]] = p. Per-row ranges stay CONTIGUOUS
// (rbase[lr]=kbase[lr*16]) so the unroll-8 hot loop is byte-identical to
// r10 -- but gathers sweep h in ascending column order, and all 782
// lockstep blocks share a ~1-2MB active window that fits per-XCD L2.
// ---------------------------------------------------------------------------
__global__ __launch_bounds__(512) void k_agg2(const unsigned* __restrict__ hbits,
                                              const uint2* __restrict__ out1,
                                              const int* __restrict__ off1T,
                                              float* __restrict__ out) {
    __shared__ uint2 stg[CAP2];            // 27648 B
    __shared__ unsigned short order[CAP2]; //  6912 B
    __shared__ unsigned short rnk[CAP2];   //  6912 B
    __shared__ int kbase[NKEY2];           //  4096 B
    __shared__ int rbase[65];
    __shared__ int wtot[8];
    const int t = threadIdx.x;
    const int b = blockIdx.x;
    const int lane = t & 63;
    const int w    = t >> 6;

    kbase[2 * t] = 0; kbase[2 * t + 1] = 0;

    // descriptors (coalesced rows of off1T)
    const int s0 = off1T[(size_t)b * NBLK + t];
    const int e0 = off1T[(size_t)(b + 1) * NBLK + t];
    int s1 = 0, e1 = 0;
    int myLen = e0 - s0;
    if (t + 512 < NBLK) {
        s1 = off1T[(size_t)b * NBLK + t + 512];
        e1 = off1T[(size_t)(b + 1) * NBLK + t + 512];
        myLen += e1 - s1;
    }

    // shuffle-based exclusive 512-scan of myLen -> staging base
    int s = myLen;
#pragma unroll
    for (int off = 1; off < 64; off <<= 1) {
        int n = __shfl_up(s, off);
        if (lane >= off) s += n;
    }
    if (lane == 63) wtot[w] = s;
    const int waveExcl = s - myLen;
    __syncthreads();
    int cross = 0;
    for (int j = 0; j < w; ++j) cross += wtot[j];
    const int base = cross + waveExcl;

    // copy segments -> LDS staging; keyed histogram + rank capture
    {
        int p = base;
        const uint2* seg = out1 + (size_t)t * CH;
        for (int i = s0; i < e0; ++i, ++p) {
            if (p < CAP2) {
                const uint2 rec = seg[i];
                stg[p] = rec;
                const int key = (int)((rec.x >> 16) & 63u) * 16 + (int)((rec.x & 0xffffu) >> 12);
                rnk[p] = (unsigned short)atomicAdd(&kbase[key], 1);
            }
        }
        if (t + 512 < NBLK) {
            const uint2* seg2 = out1 + (size_t)(t + 512) * CH;
            for (int i = s1; i < e1; ++i, ++p) {
                if (p < CAP2) {
                    const uint2 rec = seg2[i];
                    stg[p] = rec;
                    const int key = (int)((rec.x >> 16) & 63u) * 16 + (int)((rec.x & 0xffffu) >> 12);
                    rnk[p] = (unsigned short)atomicAdd(&kbase[key], 1);
                }
            }
        }
    }
    __syncthreads();

    // shuffle exclusive scan over 1024 keys (thread t owns kbase[2t..2t+1])
    {
        const int c0 = kbase[2 * t];
        const int c1 = kbase[2 * t + 1];
        const int run = c0 + c1;
        int sv = run;
#pragma unroll
        for (int off = 1; off < 64; off <<= 1) {
            int n = __shfl_up(sv, off);
            if (lane >= off) sv += n;
        }
        if (lane == 63) wtot[w] = sv;
        const int wExcl = sv - run;
        __syncthreads();
        int cr = 0;
        for (int j = 0; j < w; ++j) cr += wtot[j];
        kbase[2 * t]     = cr + wExcl;
        kbase[2 * t + 1] = cr + wExcl + c0;
        if (t == 511) rbase[64] = cr + sv;   // grand total
    }
    __syncthreads();
    if (t < 64) rbase[t] = kbase[t * 16];
    __syncthreads();

    // build column-sorted permutation, atomic-free
    {
        const int lim = (base + myLen < CAP2) ? (base + myLen) : CAP2;
        for (int p = base; p < lim; ++p) {
            const unsigned rx = stg[p].x;
            const int key = (int)((rx >> 16) & 63u) * 16 + (int)((rx & 0xffffu) >> 12);
            const int pos = kbase[key] + (int)rnk[p];
            if (pos < CAP2) order[pos] = (unsigned short)p;
        }
    }
    __syncthreads();

    // gather: wave w owns local rows w*8..w*8+7 (r10 hot loop, unchanged)
    for (int k = 0; k < 8; ++k) {
        const int lr  = (w << 3) + k;
        const int row = (b << 6) + lr;
        const int sR  = rbase[lr];
        int cnt = rbase[lr + 1] - sR;
        if (sR + cnt > CAP2) cnt = (CAP2 > sR) ? (CAP2 - sR) : 0;
        float2 acc = make_float2(0.f, 0.f);
        int i = 0;
        for (; i + 8 <= cnt; i += 8) {
            int idx8[8];
#pragma unroll
            for (int j = 0; j < 8; ++j) idx8[j] = order[sR + i + j];
            uint2 m[8];
#pragma unroll
            for (int j = 0; j < 8; ++j) m[j] = stg[idx8[j]];
            unsigned hb[8];
#pragma unroll
            for (int j = 0; j < 8; ++j)
                hb[j] = hbits[(size_t)(m[j].x & 0xffffu) * 64 + lane];
#pragma unroll
            for (int j = 0; j < 8; ++j) {
                const float v = __uint_as_float(m[j].y);
                acc.x += v * __uint_as_float(hb[j] << 16);
                acc.y += v * __uint_as_float(hb[j] & 0xffff0000u);
            }
        }
        for (; i < cnt; ++i) {
            const uint2 m = stg[order[sR + i]];
            const unsigned hbv = hbits[(size_t)(m.x & 0xffffu) * 64 + lane];
            const float v = __uint_as_float(m.y);
            acc.x += v * __uint_as_float(hbv << 16);
            acc.y += v * __uint_as_float(hbv & 0xffff0000u);
        }
        if (row < NNODES)
            ((float2*)out)[(size_t)row * 64 + lane] = acc;
    }
}

extern "C" void kernel_launch(void* const* d_in, const int* in_sizes, int n_in,
                              void* d_out, int out_size, void* d_ws, size_t ws_size,
                              hipStream_t stream) {
    const float* X     = (const float*)d_in[0];
    const float* W     = (const float*)d_in[1];
    const float* alpha = (const float*)d_in[2];
    const int*   rows  = (const int*)d_in[3];
    const int*   cols  = (const int*)d_in[4];
    const float* vals  = (const float*)d_in[5];
    float* out = (float*)d_out;

    // workspace layout
    char* ws = (char*)d_ws;
    unsigned*       hbits = (unsigned*)(ws + 0);            // 12,800,000 B
    unsigned short* hb16  = (unsigned short*)(ws + 0);      // same bytes, u16 view
    uint2*          out1  = (uint2*)(ws + 12800000);        // 19,202,048 B
    int*            off1T = (int*)  (ws + 32002048);        //  1,835,352 B (783*586*4)
    uint4*          Wf    = (uint4*)(ws + 33837408);        //     32,768 B
    // total: 33,870,176 B

    hipLaunchKernelGGL(k_wprep, dim3(1), dim3(256), 0, stream, W, Wf);
    hipLaunchKernelGGL(k_gemm, dim3(NBUK), dim3(256), 0, stream, X, Wf, hb16);
    hipLaunchKernelGGL(k_bin, dim3(NBLK), dim3(256), 0, stream,
                       rows, cols, vals, alpha, out1, off1T);
    hipLaunchKernelGGL(k_agg2, dim3(NBUK), dim3(512), 0, stream,
                       hbits, out1, off1T, out);
}